// Round 1
// baseline (38669.272 us; speedup 1.0000x reference)
//
#include <hip/hip_runtime.h>
#include <hip/hip_bf16.h>

// GRU, T=512 B=64 IC=HC=512 L=2.
// Strategy: bf16 MFMA for all matmuls, fp32 accum + fp32 gate math.
//  1) prep: fp32->bf16 conversions (x, W1, W2)
//  2) xproj (per layer): X1p = in@W1x^T + b1, X2p = in@W2x^T + b2  (parallel GEMM)
//  3) rec (per layer): persistent 64-WG kernel, recurrent weights in LDS,
//     512 steps x 2 custom grid barriers (sense-reversing, device-scope atomics).
// Workspace use ~167 MB.

#define T_STEPS 512
#define BATCH   64
#define ICH     512
#define HCH     512
#define NL      2
#define M_TOT   (T_STEPS*BATCH)   // 32768
#define N1      (2*HCH)           // 1024
#define KCAT    (ICH+HCH)         // 1024
#define NWG_REC 64

using bf16x8  = __attribute__((ext_vector_type(8))) __bf16;
using floatx4 = __attribute__((ext_vector_type(4))) float;
using uint4v  = __attribute__((ext_vector_type(4))) unsigned int;

__device__ __forceinline__ unsigned short f2bf(float f) {
    unsigned int u = __builtin_bit_cast(unsigned int, f);
    u += 0x7FFFu + ((u >> 16) & 1u);          // RNE
    return (unsigned short)(u >> 16);
}
__device__ __forceinline__ float bf2f(unsigned short s) {
    unsigned int u = ((unsigned int)s) << 16;
    return __builtin_bit_cast(float, u);
}
__device__ __forceinline__ float sigmoidf_(float x) {
    return 1.0f / (1.0f + __expf(-x));
}
__device__ __forceinline__ floatx4 mfma_bf16_16x16x32(bf16x8 a, bf16x8 b, floatx4 c) {
    return __builtin_amdgcn_mfma_f32_16x16x32_bf16(a, b, c, 0, 0, 0);
}

// ---------------------------------------------------------------- prep
__global__ void prep_kernel(const float* __restrict__ x,
                            const float* __restrict__ W1,
                            const float* __restrict__ W2,
                            unsigned short* __restrict__ xb,
                            unsigned short* __restrict__ W1b,
                            unsigned short* __restrict__ W2b) {
    const int NX  = M_TOT*ICH;
    const int NW1 = NL*N1*KCAT;
    const int NW2 = NL*HCH*KCAT;
    const int total = NX + NW1 + NW2;
    for (int i = blockIdx.x*blockDim.x + threadIdx.x; i < total;
         i += gridDim.x*blockDim.x) {
        if (i < NX)           xb[i]         = f2bf(x[i]);
        else if (i < NX+NW1)  W1b[i-NX]     = f2bf(W1[i-NX]);
        else                  W2b[i-NX-NW1] = f2bf(W2[i-NX-NW1]);
    }
}

// ---------------------------------------------------------------- xproj
// C[m,n] (n<1024 -> X1p w/ b1 ; n in [1024,1536) -> X2p w/ b2), K = 512 (x-part)
#define XP_LDP 40   // 32 + 8 pad (breaks LDS bank conflicts)
__global__ void __launch_bounds__(256)
xproj_kernel(int layer,
             const unsigned short* __restrict__ Ab,   // [32768][512] bf16
             const unsigned short* __restrict__ W1b,  // [L][1024][1024]
             const unsigned short* __restrict__ W2b,  // [L][512][1024]
             const float* __restrict__ b1,
             const float* __restrict__ b2,
             unsigned short* __restrict__ X1p,        // [32768][1024] bf16
             unsigned short* __restrict__ X2p) {      // [32768][512]  bf16
    __shared__ unsigned short Ash[128*XP_LDP];
    __shared__ unsigned short Bsh[128*XP_LDP];
    const int nb = blockIdx.x;           // 0..11  (12 * 128 = 1536 cols)
    const int mb = blockIdx.y;           // 0..255
    const int tid = threadIdx.x;
    const int lane = tid & 63;
    const int wv = tid >> 6;
    const int wr = (wv >> 1) * 64;
    const int wc = (wv & 1) * 64;
    const int rfrag = lane & 15;
    const int koff = (lane >> 4) * 8;
    const int n0 = nb * 128;

    floatx4 acc[4][4];
    #pragma unroll
    for (int i=0;i<4;i++)
        #pragma unroll
        for (int j=0;j<4;j++) acc[i][j] = (floatx4)(0.0f);

    for (int kc = 0; kc < ICH/32; ++kc) {
        #pragma unroll
        for (int c = 0; c < 2; ++c) {
            int chunk = tid + c*256;
            int row = chunk >> 2;
            int c8  = (chunk & 3) * 8;
            *reinterpret_cast<uint4v*>(&Ash[row*XP_LDP + c8]) =
                *reinterpret_cast<const uint4v*>(&Ab[(size_t)(mb*128 + row)*ICH + kc*32 + c8]);
            int nrow = n0 + row;
            const unsigned short* bsrc = (nrow < N1)
                ? (W1b + (size_t)(layer*N1 + nrow)*KCAT + kc*32 + c8)
                : (W2b + (size_t)(layer*HCH + (nrow - N1))*KCAT + kc*32 + c8);
            *reinterpret_cast<uint4v*>(&Bsh[row*XP_LDP + c8]) =
                *reinterpret_cast<const uint4v*>(bsrc);
        }
        __syncthreads();
        bf16x8 af[4], bfr[4];
        #pragma unroll
        for (int mt=0; mt<4; ++mt)
            af[mt] = *reinterpret_cast<const bf16x8*>(&Ash[(wr + mt*16 + rfrag)*XP_LDP + koff]);
        #pragma unroll
        for (int nt=0; nt<4; ++nt)
            bfr[nt] = *reinterpret_cast<const bf16x8*>(&Bsh[(wc + nt*16 + rfrag)*XP_LDP + koff]);
        #pragma unroll
        for (int mt=0; mt<4; ++mt)
            #pragma unroll
            for (int nt=0; nt<4; ++nt)
                acc[mt][nt] = mfma_bf16_16x16x32(af[mt], bfr[nt], acc[mt][nt]);
        __syncthreads();
    }

    const int col0 = lane & 15;
    const int row0 = (lane >> 4) * 4;   // C/D: col=lane&15, row=(lane>>4)*4+reg
    #pragma unroll
    for (int mt=0; mt<4; ++mt) {
        #pragma unroll
        for (int nt=0; nt<4; ++nt) {
            int n = n0 + wc + nt*16 + col0;
            #pragma unroll
            for (int r=0; r<4; ++r) {
                int m = mb*128 + wr + mt*16 + row0 + r;
                float v = acc[mt][nt][r];
                if (n < N1) {
                    v += b1[layer*N1 + n];
                    X1p[(size_t)m*N1 + n] = f2bf(v);
                } else {
                    v += b2[layer*HCH + (n - N1)];
                    X2p[(size_t)m*HCH + (n - N1)] = f2bf(v);
                }
            }
        }
    }
}

// ---------------------------------------------------------------- grid barrier
__device__ __forceinline__ void gbar(int* cnt, int* gen, int nwg) {
    __threadfence();                 // release our writes to agent scope
    __syncthreads();
    if (threadIdx.x == 0) {
        int g = __hip_atomic_load(gen, __ATOMIC_RELAXED, __HIP_MEMORY_SCOPE_AGENT);
        int a = __hip_atomic_fetch_add(cnt, 1, __ATOMIC_ACQ_REL, __HIP_MEMORY_SCOPE_AGENT);
        if (a == nwg - 1) {
            __hip_atomic_store(cnt, 0, __ATOMIC_RELAXED, __HIP_MEMORY_SCOPE_AGENT);
            __hip_atomic_fetch_add(gen, 1, __ATOMIC_ACQ_REL, __HIP_MEMORY_SCOPE_AGENT);
        } else {
            while (__hip_atomic_load(gen, __ATOMIC_RELAXED, __HIP_MEMORY_SCOPE_AGENT) == g)
                __builtin_amdgcn_s_sleep(1);
        }
    }
    __syncthreads();
    __threadfence();                 // acquire (CU-wide L1 invalidate)
}

// ---------------------------------------------------------------- recurrence
// 64 persistent WGs. Phase A: WG w owns gate cols [w*16, w*16+16) of the 1024
// (w<32 -> r cols, w>=32 -> z cols). Phase B: WG w<32 owns h cols [w*16,+16).
// Recurrent weight slices live in LDS, blocked [kblk][col][8] for clean
// ds_read_b128 MFMA B-fragments.
__global__ void __launch_bounds__(256)
rec_kernel(int layer,
           const unsigned short* __restrict__ X1p,   // [32768][1024] bf16
           const unsigned short* __restrict__ X2p,   // [32768][512]  bf16
           const unsigned short* __restrict__ W1b,
           const unsigned short* __restrict__ W2b,
           const float* __restrict__ hiddens,        // [L][1][512]
           float* h_f32, unsigned short* h_bf,
           unsigned short* rh_bf, float* z_f32,
           unsigned short* y_bf,      // layer0: bf16 seq out (feeds layer1 xproj)
           float* y_f32,              // layer1: d_out sequence
           float* hs_out,             // final hidden dest (d_out hs region)
           int* bar_cnt, int* bar_gen) {
    __shared__ unsigned short Wa[64*16*8];   // 16KB: W1h slice, blocked
    __shared__ unsigned short Wb[64*16*8];   // 16KB: W2h slice, blocked
    const int w = blockIdx.x;
    const int tid = threadIdx.x;
    const int lane = tid & 63;
    const int wv = tid >> 6;
    const int jbase = w * 16;
    const int cbase = (w & 31) * 16;
    const int rfrag = lane & 15;
    const int quad  = lane >> 4;
    const int koff0 = quad * 8;
    const int arow  = wv*16 + rfrag;    // A-fragment row (batch idx)
    const int crow0 = wv*16 + quad*4;   // first owned C row

    // stage weight slices (once per launch)
    for (int f = tid; f < 1024; f += 256) {
        int kblk = f >> 4, c = f & 15;
        *reinterpret_cast<uint4v*>(&Wa[f*8]) =
            *reinterpret_cast<const uint4v*>(
                &W1b[(size_t)(layer*N1 + jbase + c)*KCAT + ICH + kblk*8]);
    }
    if (w < 32) {
        for (int f = tid; f < 1024; f += 256) {
            int kblk = f >> 4, c = f & 15;
            *reinterpret_cast<uint4v*>(&Wb[f*8]) =
                *reinterpret_cast<const uint4v*>(
                    &W2b[(size_t)(layer*HCH + cbase + c)*KCAT + ICH + kblk*8]);
        }
    }
    // broadcast-init h over batch
    for (int i = w*256 + tid; i < BATCH*HCH; i += NWG_REC*256) {
        float v = hiddens[layer*HCH + (i & (HCH-1))];
        h_f32[i] = v;
        h_bf[i]  = f2bf(v);
    }
    gbar(bar_cnt, bar_gen, NWG_REC);

    for (int t = 0; t < T_STEPS; ++t) {
        const int mrow = t*BATCH;
        // ---------------- phase A: pre = X1p + h @ W1h^T ----------------
        float xinit[4];
        {
            int col = jbase + rfrag;
            #pragma unroll
            for (int r=0;r<4;++r)
                xinit[r] = bf2f(X1p[(size_t)(mrow + crow0 + r)*N1 + col]);
        }
        floatx4 acc = (floatx4)(0.0f);
        #pragma unroll
        for (int ks=0; ks<16; ++ks) {
            bf16x8 a = *reinterpret_cast<const bf16x8*>(&h_bf[arow*HCH + ks*32 + koff0]);
            bf16x8 b = *reinterpret_cast<const bf16x8*>(&Wa[((ks*4 + quad)*16 + rfrag)*8]);
            acc = mfma_bf16_16x16x32(a, b, acc);
        }
        if (w < 32) {               // r-gate cols: write rh = sigmoid(pre)*h
            int j = jbase + rfrag;
            #pragma unroll
            for (int r=0;r<4;++r) {
                int brow = crow0 + r;
                float rv = sigmoidf_(acc[r] + xinit[r]);
                float rh = rv * h_f32[brow*HCH + j];
                rh_bf[brow*HCH + j] = f2bf(rh);
            }
        } else {                    // z-gate cols
            int j = jbase + rfrag - HCH;
            #pragma unroll
            for (int r=0;r<4;++r) {
                int brow = crow0 + r;
                z_f32[brow*HCH + j] = sigmoidf_(acc[r] + xinit[r]);
            }
        }
        gbar(bar_cnt, bar_gen, NWG_REC);

        // ---------------- phase B: g = tanh(X2p + rh @ W2h^T); h update ----
        if (w < 32) {
            int col = cbase + rfrag;
            float x2init[4];
            #pragma unroll
            for (int r=0;r<4;++r)
                x2init[r] = bf2f(X2p[(size_t)(mrow + crow0 + r)*HCH + col]);
            floatx4 acc2 = (floatx4)(0.0f);
            #pragma unroll
            for (int ks=0; ks<16; ++ks) {
                bf16x8 a = *reinterpret_cast<const bf16x8*>(&rh_bf[arow*HCH + ks*32 + koff0]);
                bf16x8 b = *reinterpret_cast<const bf16x8*>(&Wb[((ks*4 + quad)*16 + rfrag)*8]);
                acc2 = mfma_bf16_16x16x32(a, b, acc2);
            }
            #pragma unroll
            for (int r=0;r<4;++r) {
                int brow = crow0 + r;
                float g  = tanhf(acc2[r] + x2init[r]);
                float z  = z_f32[brow*HCH + col];
                float ho = h_f32[brow*HCH + col];
                float hn = z*ho + (1.0f - z)*g;
                h_f32[brow*HCH + col] = hn;
                h_bf[brow*HCH + col]  = f2bf(hn);
                if (layer == 0)
                    y_bf[(size_t)(mrow + brow)*HCH + col] = f2bf(hn);
                else
                    y_f32[(size_t)(mrow + brow)*HCH + col] = hn;
                if (t == T_STEPS-1)
                    hs_out[brow*HCH + col] = hn;
            }
        }
        gbar(bar_cnt, bar_gen, NWG_REC);
    }
}

// ---------------------------------------------------------------- launch
extern "C" void kernel_launch(void* const* d_in, const int* in_sizes, int n_in,
                              void* d_out, int out_size, void* d_ws, size_t ws_size,
                              hipStream_t stream) {
    const float* x       = (const float*)d_in[0];
    const float* hiddens = (const float*)d_in[1];
    const float* W1      = (const float*)d_in[2];
    const float* b1      = (const float*)d_in[3];
    const float* W2      = (const float*)d_in[4];
    const float* b2      = (const float*)d_in[5];
    float* out = (float*)d_out;                    // [T][B][HC]
    float* hs  = out + (size_t)M_TOT*HCH;          // [L][B][HC]

    char* ws = (char*)d_ws;
    size_t off = 0;
    auto alloc = [&](size_t bytes) -> char* {
        char* p = ws + off; off += (bytes + 255) & ~(size_t)255; return p;
    };
    int*            bar   = (int*)          alloc(1024);
    float*          h_f32 = (float*)        alloc((size_t)BATCH*HCH*4);
    unsigned short* h_bf  = (unsigned short*)alloc((size_t)BATCH*HCH*2);
    unsigned short* rh_bf = (unsigned short*)alloc((size_t)BATCH*HCH*2);
    float*          z_f32 = (float*)        alloc((size_t)BATCH*HCH*4);
    unsigned short* W1b   = (unsigned short*)alloc((size_t)NL*N1*KCAT*2);
    unsigned short* W2b   = (unsigned short*)alloc((size_t)NL*HCH*KCAT*2);
    unsigned short* xb    = (unsigned short*)alloc((size_t)M_TOT*ICH*2);
    unsigned short* y1b   = (unsigned short*)alloc((size_t)M_TOT*HCH*2);
    unsigned short* X1p   = (unsigned short*)alloc((size_t)M_TOT*N1*2);
    unsigned short* X2p   = (unsigned short*)alloc((size_t)M_TOT*HCH*2);

    hipMemsetAsync(bar, 0, 1024, stream);
    prep_kernel<<<2048, 256, 0, stream>>>(x, W1, W2, xb, W1b, W2b);

    xproj_kernel<<<dim3(12, 256), 256, 0, stream>>>(0, xb, W1b, W2b, b1, b2, X1p, X2p);
    rec_kernel<<<NWG_REC, 256, 0, stream>>>(0, X1p, X2p, W1b, W2b, hiddens,
        h_f32, h_bf, rh_bf, z_f32, y1b, out, hs, bar, bar + 1);

    xproj_kernel<<<dim3(12, 256), 256, 0, stream>>>(1, y1b, W1b, W2b, b1, b2, X1p, X2p);
    rec_kernel<<<NWG_REC, 256, 0, stream>>>(1, X1p, X2p, W1b, W2b, hiddens,
        h_f32, h_bf, rh_bf, z_f32, y1b, out, hs + BATCH*HCH, bar + 16, bar + 17);
}

// Round 2
// 20859.073 us; speedup vs baseline: 1.8538x; 1.8538x over previous
//
#include <hip/hip_runtime.h>
#include <hip/hip_bf16.h>

// GRU T=512 B=64 IC=HC=512 L=2 — round 2.
// R1: 37.8us/step, barrier-bound (threadfence = full L2 wb/inv per phase).
// R2: (a) fence-free data path: relaxed agent-scope atomics (sc-bypass to L3)
//     for all cross-WG state; barrier = syncthreads + monotonic fetch_add + spin.
//     (b) both layers fused in ONE persistent kernel, layer1 lags layer0 by one
//     step; layer1's x-projection folded into its K=1024 gate MFMA (no 2nd
//     xproj, no 2nd rec). 64 WGs x 512 thr, 2 barriers per super-step, 513
//     super-steps.

#define T_STEPS 512
#define BATCH   64
#define ICH     512
#define HCH     512
#define NL      2
#define M_TOT   (T_STEPS*BATCH)   // 32768
#define N1      (2*HCH)           // 1024
#define KCAT    (ICH+HCH)         // 1024
#define NWG     64
#define NTHR    512

using bf16x8  = __attribute__((ext_vector_type(8))) __bf16;
using floatx4 = __attribute__((ext_vector_type(4))) float;
using uint4v  = __attribute__((ext_vector_type(4))) unsigned int;

__device__ __forceinline__ unsigned short f2bf(float f) {
    unsigned int u = __builtin_bit_cast(unsigned int, f);
    u += 0x7FFFu + ((u >> 16) & 1u);          // RNE
    return (unsigned short)(u >> 16);
}
__device__ __forceinline__ float bf2f(unsigned short s) {
    unsigned int u = ((unsigned int)s) << 16;
    return __builtin_bit_cast(float, u);
}
__device__ __forceinline__ float sigmoidf_(float x) {
    return 1.0f / (1.0f + __expf(-x));
}
__device__ __forceinline__ floatx4 mfma_bf16(bf16x8 a, bf16x8 b, floatx4 c) {
    return __builtin_amdgcn_mfma_f32_16x16x32_bf16(a, b, c, 0, 0, 0);
}

// coherent (device-scope, cache-bypassing) accessors — no fences needed
__device__ __forceinline__ bf16x8 ld_frag_co(const unsigned short* p) {
    union { unsigned long long q[2]; bf16x8 v; } u;
    u.q[0] = __hip_atomic_load((const unsigned long long*)p,
                               __ATOMIC_RELAXED, __HIP_MEMORY_SCOPE_AGENT);
    u.q[1] = __hip_atomic_load(((const unsigned long long*)p) + 1,
                               __ATOMIC_RELAXED, __HIP_MEMORY_SCOPE_AGENT);
    return u.v;
}
__device__ __forceinline__ void st_word_co(unsigned short* p, unsigned int w) {
    __hip_atomic_store((unsigned int*)p, w, __ATOMIC_RELAXED, __HIP_MEMORY_SCOPE_AGENT);
}

// ---------------------------------------------------------------- prep
__global__ void prep_kernel(const float* __restrict__ x,
                            const float* __restrict__ W1,
                            const float* __restrict__ W2,
                            unsigned short* __restrict__ xb,
                            unsigned short* __restrict__ W1b,
                            unsigned short* __restrict__ W2b) {
    const int NX  = M_TOT*ICH;
    const int NW1 = NL*N1*KCAT;
    const int NW2 = NL*HCH*KCAT;
    const int total = NX + NW1 + NW2;
    for (int i = blockIdx.x*blockDim.x + threadIdx.x; i < total;
         i += gridDim.x*blockDim.x) {
        if (i < NX)           xb[i]         = f2bf(x[i]);
        else if (i < NX+NW1)  W1b[i-NX]     = f2bf(W1[i-NX]);
        else                  W2b[i-NX-NW1] = f2bf(W2[i-NX-NW1]);
    }
}

// ---------------------------------------------------------------- xproj (layer 0 only)
#define XP_LDP 40
__global__ void __launch_bounds__(256)
xproj_kernel(int layer,
             const unsigned short* __restrict__ Ab,
             const unsigned short* __restrict__ W1b,
             const unsigned short* __restrict__ W2b,
             const float* __restrict__ b1,
             const float* __restrict__ b2,
             unsigned short* __restrict__ X1p,
             unsigned short* __restrict__ X2p) {
    __shared__ unsigned short Ash[128*XP_LDP];
    __shared__ unsigned short Bsh[128*XP_LDP];
    const int nb = blockIdx.x;
    const int mb = blockIdx.y;
    const int tid = threadIdx.x;
    const int lane = tid & 63;
    const int wv = tid >> 6;
    const int wr = (wv >> 1) * 64;
    const int wc = (wv & 1) * 64;
    const int rfrag = lane & 15;
    const int koff = (lane >> 4) * 8;
    const int n0 = nb * 128;

    floatx4 acc[4][4];
    #pragma unroll
    for (int i=0;i<4;i++)
        #pragma unroll
        for (int j=0;j<4;j++) acc[i][j] = (floatx4)(0.0f);

    for (int kc = 0; kc < ICH/32; ++kc) {
        #pragma unroll
        for (int c = 0; c < 2; ++c) {
            int chunk = tid + c*256;
            int row = chunk >> 2;
            int c8  = (chunk & 3) * 8;
            *reinterpret_cast<uint4v*>(&Ash[row*XP_LDP + c8]) =
                *reinterpret_cast<const uint4v*>(&Ab[(size_t)(mb*128 + row)*ICH + kc*32 + c8]);
            int nrow = n0 + row;
            const unsigned short* bsrc = (nrow < N1)
                ? (W1b + (size_t)(layer*N1 + nrow)*KCAT + kc*32 + c8)
                : (W2b + (size_t)(layer*HCH + (nrow - N1))*KCAT + kc*32 + c8);
            *reinterpret_cast<uint4v*>(&Bsh[row*XP_LDP + c8]) =
                *reinterpret_cast<const uint4v*>(bsrc);
        }
        __syncthreads();
        bf16x8 af[4], bfr[4];
        #pragma unroll
        for (int mt=0; mt<4; ++mt)
            af[mt] = *reinterpret_cast<const bf16x8*>(&Ash[(wr + mt*16 + rfrag)*XP_LDP + koff]);
        #pragma unroll
        for (int nt=0; nt<4; ++nt)
            bfr[nt] = *reinterpret_cast<const bf16x8*>(&Bsh[(wc + nt*16 + rfrag)*XP_LDP + koff]);
        #pragma unroll
        for (int mt=0; mt<4; ++mt)
            #pragma unroll
            for (int nt=0; nt<4; ++nt)
                acc[mt][nt] = mfma_bf16(af[mt], bfr[nt], acc[mt][nt]);
        __syncthreads();
    }

    const int col0 = lane & 15;
    const int row0 = (lane >> 4) * 4;
    #pragma unroll
    for (int mt=0; mt<4; ++mt) {
        #pragma unroll
        for (int nt=0; nt<4; ++nt) {
            int n = n0 + wc + nt*16 + col0;
            #pragma unroll
            for (int r=0; r<4; ++r) {
                int m = mb*128 + wr + mt*16 + row0 + r;
                float v = acc[mt][nt][r];
                if (n < N1) {
                    v += b1[layer*N1 + n];
                    X1p[(size_t)m*N1 + n] = f2bf(v);
                } else {
                    v += b2[layer*HCH + (n - N1)];
                    X2p[(size_t)m*HCH + (n - N1)] = f2bf(v);
                }
            }
        }
    }
}

// ---------------------------------------------------------------- fast grid barrier
// monotonic round counter; data coherence handled by sc-bypassing accessors.
__device__ __forceinline__ void gbar(unsigned int* cnt, unsigned int* gen,
                                     unsigned int round) {
    __syncthreads();    // drains vmcnt: all coherent stores are at the L3 point
    if (threadIdx.x == 0) {
        unsigned a = __hip_atomic_fetch_add(cnt, 1u, __ATOMIC_RELEASE,
                                            __HIP_MEMORY_SCOPE_AGENT);
        if (a == round*NWG - 1u) {
            __hip_atomic_store(gen, round, __ATOMIC_RELEASE,
                               __HIP_MEMORY_SCOPE_AGENT);
        } else {
            while (__hip_atomic_load(gen, __ATOMIC_RELAXED,
                                     __HIP_MEMORY_SCOPE_AGENT) < round)
                __builtin_amdgcn_s_sleep(1);
        }
    }
    __syncthreads();
}

// ---------------------------------------------------------------- fused recurrence
// WG w<32: layer 0, owns h cols [w*16,+16). WG w>=32: layer 1 (lag 1 step),
// x-projection folded into K=1024 MFMA over concat(y0, h1).
// waves 0-3 (ct=0): r-gate cols + phase-B h-update (h, z ownership aligned so
// h stays in registers, z in LDS). waves 4-7 (ct=1): z-gate cols.
__global__ void __launch_bounds__(NTHR, 2)
rec_fused(const unsigned short* __restrict__ X1p,   // [32768][1024] bf16 (L0)
          const unsigned short* __restrict__ X2p,   // [32768][512]  bf16 (L0)
          const unsigned short* __restrict__ W1b,   // [L][1024][1024] bf16
          const unsigned short* __restrict__ W2b,   // [L][512][1024]  bf16
          const float* __restrict__ b1,
          const float* __restrict__ b2,
          const float* __restrict__ hiddens,        // [L][512]
          unsigned short* __restrict__ y0seq,       // [513][64][512] bf16 (slot t = h0 after step t-1)
          unsigned short* __restrict__ h1b,         // [64][512] bf16
          unsigned short* __restrict__ rh0,         // [64][512] bf16
          unsigned short* __restrict__ rh1,         // [64][512] bf16
          float* __restrict__ out,                  // [512][64][512] f32
          float* __restrict__ hs,                   // [2][64][512]  f32
          unsigned int* __restrict__ cnt, unsigned int* __restrict__ gen) {
    __shared__ float zsh[BATCH*16];
    const int w     = blockIdx.x;
    const int tid   = threadIdx.x;
    const int lane  = tid & 63;
    const int v     = tid >> 6;
    const int rt    = v & 3;
    const int ct    = v >> 2;
    const int rfrag = lane & 15;
    const int quad  = lane >> 4;
    const int layer = (w >= 32) ? 1 : 0;
    const int c0    = (w & 31) * 16;
    const int arow  = rt*16 + rfrag;      // A-frag row (batch)
    const int crow  = rt*16 + quad*4;     // first owned C row
    const int ccol  = c0 + rfrag;         // owned col
    const int gcol  = (ct ? HCH : 0) + ccol;  // gate col in [0,1024)

    float hreg[4];
    #pragma unroll
    for (int r=0;r<4;++r) hreg[r] = hiddens[layer*HCH + ccol];
    const float bias1 = b1[(size_t)layer*N1 + gcol];   // used by L1 only
    const float bias2 = b2[(size_t)layer*HCH + ccol];  // used by L1 only

    // init h state (coherent pair-stores, even lanes carry (col, col+1))
    if (ct == 0) {
        unsigned short* dst = layer ? h1b : y0seq;     // y0seq slot 0
        #pragma unroll
        for (int r=0;r<4;++r) {
            unsigned short me = f2bf(hreg[r]);
            unsigned ot = (unsigned)__shfl_xor((int)(unsigned)me, 1, 64);
            if (!(lane & 1))
                st_word_co(&dst[(crow+r)*HCH + ccol], (unsigned)me | (ot << 16));
        }
    }
    unsigned rnd = 0;
    gbar(cnt, gen, ++rnd);

    for (int s = 0; s <= T_STEPS; ++s) {
        const int tt     = layer ? (s - 1) : s;           // this WG's timestep
        const int active = layer ? (s >= 1) : (s < T_STEPS);
        const unsigned short* aseq = y0seq + (size_t)s*BATCH*HCH;  // h0(t0-1) == y0(t1)

        // ---------------- phase A: gate pre-activations ----------------
        if (active) {
            floatx4 acc = (floatx4)(0.0f);
            const unsigned short* wrow = W1b + ((size_t)layer*N1 + gcol)*KCAT;
            if (!layer) {
                #pragma unroll
                for (int ks=0; ks<16; ++ks) {
                    bf16x8 a = ld_frag_co(&aseq[arow*HCH + ks*32 + quad*8]);
                    bf16x8 b = *reinterpret_cast<const bf16x8*>(&wrow[ICH + ks*32 + quad*8]);
                    acc = mfma_bf16(a, b, acc);
                }
            } else {
                #pragma unroll
                for (int ks=0; ks<16; ++ks) {           // k<512: y0(t1)
                    bf16x8 a = ld_frag_co(&aseq[arow*HCH + ks*32 + quad*8]);
                    bf16x8 b = *reinterpret_cast<const bf16x8*>(&wrow[ks*32 + quad*8]);
                    acc = mfma_bf16(a, b, acc);
                }
                #pragma unroll
                for (int ks=0; ks<16; ++ks) {           // k>=512: h1(t1-1)
                    bf16x8 a = ld_frag_co(&h1b[arow*HCH + ks*32 + quad*8]);
                    bf16x8 b = *reinterpret_cast<const bf16x8*>(&wrow[ICH + ks*32 + quad*8]);
                    acc = mfma_bf16(a, b, acc);
                }
            }
            float pre[4];
            if (!layer) {
                #pragma unroll
                for (int r=0;r<4;++r)
                    pre[r] = acc[r] + bf2f(X1p[(size_t)(tt*BATCH + crow + r)*N1 + gcol]);
            } else {
                #pragma unroll
                for (int r=0;r<4;++r) pre[r] = acc[r] + bias1;
            }
            if (ct == 0) {          // r-gate: rh = sigmoid(pre)*h  (h in regs)
                unsigned short* rbuf = layer ? rh1 : rh0;
                #pragma unroll
                for (int r=0;r<4;++r) {
                    float rh = sigmoidf_(pre[r]) * hreg[r];
                    unsigned short me = f2bf(rh);
                    unsigned ot = (unsigned)__shfl_xor((int)(unsigned)me, 1, 64);
                    if (!(lane & 1))
                        st_word_co(&rbuf[(crow+r)*HCH + ccol], (unsigned)me | (ot << 16));
                }
            } else {                // z-gate -> LDS
                #pragma unroll
                for (int r=0;r<4;++r)
                    zsh[(crow+r)*16 + rfrag] = sigmoidf_(pre[r]);
            }
        }
        gbar(cnt, gen, ++rnd);

        // ---------------- phase B: g = tanh(...), h update ----------------
        if (active && ct == 0) {
            floatx4 acc = (floatx4)(0.0f);
            const unsigned short* w2row = W2b + ((size_t)layer*HCH + ccol)*KCAT;
            const unsigned short* rbuf = layer ? rh1 : rh0;
            if (!layer) {
                #pragma unroll
                for (int ks=0; ks<16; ++ks) {
                    bf16x8 a = ld_frag_co(&rbuf[arow*HCH + ks*32 + quad*8]);
                    bf16x8 b = *reinterpret_cast<const bf16x8*>(&w2row[ICH + ks*32 + quad*8]);
                    acc = mfma_bf16(a, b, acc);
                }
            } else {
                #pragma unroll
                for (int ks=0; ks<16; ++ks) {           // k<512: y0(t1)
                    bf16x8 a = ld_frag_co(&aseq[arow*HCH + ks*32 + quad*8]);
                    bf16x8 b = *reinterpret_cast<const bf16x8*>(&w2row[ks*32 + quad*8]);
                    acc = mfma_bf16(a, b, acc);
                }
                #pragma unroll
                for (int ks=0; ks<16; ++ks) {           // k>=512: rh1
                    bf16x8 a = ld_frag_co(&rbuf[arow*HCH + ks*32 + quad*8]);
                    bf16x8 b = *reinterpret_cast<const bf16x8*>(&w2row[ICH + ks*32 + quad*8]);
                    acc = mfma_bf16(a, b, acc);
                }
            }
            unsigned short* hdst = layer ? h1b
                                         : (y0seq + (size_t)(tt+1)*BATCH*HCH);
            #pragma unroll
            for (int r=0;r<4;++r) {
                float x2 = layer ? bias2
                                 : bf2f(X2p[(size_t)(tt*BATCH + crow + r)*HCH + ccol]);
                float g  = tanhf(acc[r] + x2);
                float z  = zsh[(crow+r)*16 + rfrag];
                float hn = z*hreg[r] + (1.0f - z)*g;
                hreg[r] = hn;
                unsigned short me = f2bf(hn);
                unsigned ot = (unsigned)__shfl_xor((int)(unsigned)me, 1, 64);
                if (!(lane & 1))
                    st_word_co(&hdst[(crow+r)*HCH + ccol], (unsigned)me | (ot << 16));
                if (layer)
                    out[((size_t)tt*BATCH + crow + r)*HCH + ccol] = hn;
                if (tt == T_STEPS-1)
                    hs[(size_t)layer*BATCH*HCH + (crow+r)*HCH + ccol] = hn;
            }
        }
        gbar(cnt, gen, ++rnd);
    }
}

// ---------------------------------------------------------------- launch
extern "C" void kernel_launch(void* const* d_in, const int* in_sizes, int n_in,
                              void* d_out, int out_size, void* d_ws, size_t ws_size,
                              hipStream_t stream) {
    const float* x       = (const float*)d_in[0];
    const float* hiddens = (const float*)d_in[1];
    const float* W1      = (const float*)d_in[2];
    const float* b1      = (const float*)d_in[3];
    const float* W2      = (const float*)d_in[4];
    const float* b2      = (const float*)d_in[5];
    float* out = (float*)d_out;                    // [T][B][HC]
    float* hs  = out + (size_t)M_TOT*HCH;          // [L][B][HC]

    char* ws = (char*)d_ws;
    size_t off = 0;
    auto alloc = [&](size_t bytes) -> char* {
        char* p = ws + off; off += (bytes + 255) & ~(size_t)255; return p;
    };
    unsigned int*   bar   = (unsigned int*) alloc(1024);
    unsigned short* h1b   = (unsigned short*)alloc((size_t)BATCH*HCH*2);
    unsigned short* rh0   = (unsigned short*)alloc((size_t)BATCH*HCH*2);
    unsigned short* rh1   = (unsigned short*)alloc((size_t)BATCH*HCH*2);
    unsigned short* W1b   = (unsigned short*)alloc((size_t)NL*N1*KCAT*2);
    unsigned short* W2b   = (unsigned short*)alloc((size_t)NL*HCH*KCAT*2);
    unsigned short* xb    = (unsigned short*)alloc((size_t)M_TOT*ICH*2);
    unsigned short* X1p   = (unsigned short*)alloc((size_t)M_TOT*N1*2);
    unsigned short* X2p   = (unsigned short*)alloc((size_t)M_TOT*HCH*2);
    unsigned short* y0seq = (unsigned short*)alloc((size_t)(T_STEPS+1)*BATCH*HCH*2);

    hipMemsetAsync(bar, 0, 1024, stream);
    prep_kernel<<<2048, 256, 0, stream>>>(x, W1, W2, xb, W1b, W2b);
    xproj_kernel<<<dim3(12, 256), 256, 0, stream>>>(0, xb, W1b, W2b, b1, b2, X1p, X2p);
    rec_fused<<<NWG, NTHR, 0, stream>>>(X1p, X2p, W1b, W2b, b1, b2, hiddens,
        y0seq, h1b, rh0, rh1, out, hs, bar, bar + 1);
}

// Round 3
// 18000.542 us; speedup vs baseline: 2.1482x; 1.1588x over previous
//
#include <hip/hip_runtime.h>
#include <hip/hip_bf16.h>

// GRU T=512 B=64 IC=HC=512 L=2 — round 3.
// R1: 18.9us/barrier (threadfence = L2 wb/inv tag-walk).
// R2: 20.2us/barrier — RELEASE agent atomics STILL emit buffer_wbl2 (L2
//     tag-walk ~32k cycles = the ~20us constant). Data path was already
//     fence-free (sc1 relaxed atomics -> L3 coherence point).
// R3: barrier made fully RELAXED (no cache maintenance anywhere). Ordering
//     argument: __syncthreads drains vmcnt(0), so each WG's sc1 stores are at
//     L3 before its arrive fetch_add issues; gen is written only after all 64
//     arrivals -> transitively all data visible to any WG that observes gen.
//     cnt/gen moved to separate cache lines.

#define T_STEPS 512
#define BATCH   64
#define ICH     512
#define HCH     512
#define NL      2
#define M_TOT   (T_STEPS*BATCH)   // 32768
#define N1      (2*HCH)           // 1024
#define KCAT    (ICH+HCH)         // 1024
#define NWG     64
#define NTHR    512

using bf16x8  = __attribute__((ext_vector_type(8))) __bf16;
using floatx4 = __attribute__((ext_vector_type(4))) float;
using uint4v  = __attribute__((ext_vector_type(4))) unsigned int;

__device__ __forceinline__ unsigned short f2bf(float f) {
    unsigned int u = __builtin_bit_cast(unsigned int, f);
    u += 0x7FFFu + ((u >> 16) & 1u);          // RNE
    return (unsigned short)(u >> 16);
}
__device__ __forceinline__ float bf2f(unsigned short s) {
    unsigned int u = ((unsigned int)s) << 16;
    return __builtin_bit_cast(float, u);
}
__device__ __forceinline__ float sigmoidf_(float x) {
    return 1.0f / (1.0f + __expf(-x));
}
__device__ __forceinline__ floatx4 mfma_bf16(bf16x8 a, bf16x8 b, floatx4 c) {
    return __builtin_amdgcn_mfma_f32_16x16x32_bf16(a, b, c, 0, 0, 0);
}

// coherent (L2-bypassing, relaxed) accessors — no cache maintenance
__device__ __forceinline__ bf16x8 ld_frag_co(const unsigned short* p) {
    union { unsigned long long q[2]; bf16x8 v; } u;
    u.q[0] = __hip_atomic_load((const unsigned long long*)p,
                               __ATOMIC_RELAXED, __HIP_MEMORY_SCOPE_AGENT);
    u.q[1] = __hip_atomic_load(((const unsigned long long*)p) + 1,
                               __ATOMIC_RELAXED, __HIP_MEMORY_SCOPE_AGENT);
    return u.v;
}
__device__ __forceinline__ void st_word_co(unsigned short* p, unsigned int w) {
    __hip_atomic_store((unsigned int*)p, w, __ATOMIC_RELAXED, __HIP_MEMORY_SCOPE_AGENT);
}

// ---------------------------------------------------------------- prep
__global__ void prep_kernel(const float* __restrict__ x,
                            const float* __restrict__ W1,
                            const float* __restrict__ W2,
                            unsigned short* __restrict__ xb,
                            unsigned short* __restrict__ W1b,
                            unsigned short* __restrict__ W2b) {
    const int NX  = M_TOT*ICH;
    const int NW1 = NL*N1*KCAT;
    const int NW2 = NL*HCH*KCAT;
    const int total = NX + NW1 + NW2;
    for (int i = blockIdx.x*blockDim.x + threadIdx.x; i < total;
         i += gridDim.x*blockDim.x) {
        if (i < NX)           xb[i]         = f2bf(x[i]);
        else if (i < NX+NW1)  W1b[i-NX]     = f2bf(W1[i-NX]);
        else                  W2b[i-NX-NW1] = f2bf(W2[i-NX-NW1]);
    }
}

// ---------------------------------------------------------------- xproj (layer 0 only)
#define XP_LDP 40
__global__ void __launch_bounds__(256)
xproj_kernel(int layer,
             const unsigned short* __restrict__ Ab,
             const unsigned short* __restrict__ W1b,
             const unsigned short* __restrict__ W2b,
             const float* __restrict__ b1,
             const float* __restrict__ b2,
             unsigned short* __restrict__ X1p,
             unsigned short* __restrict__ X2p) {
    __shared__ unsigned short Ash[128*XP_LDP];
    __shared__ unsigned short Bsh[128*XP_LDP];
    const int nb = blockIdx.x;
    const int mb = blockIdx.y;
    const int tid = threadIdx.x;
    const int lane = tid & 63;
    const int wv = tid >> 6;
    const int wr = (wv >> 1) * 64;
    const int wc = (wv & 1) * 64;
    const int rfrag = lane & 15;
    const int koff = (lane >> 4) * 8;
    const int n0 = nb * 128;

    floatx4 acc[4][4];
    #pragma unroll
    for (int i=0;i<4;i++)
        #pragma unroll
        for (int j=0;j<4;j++) acc[i][j] = (floatx4)(0.0f);

    for (int kc = 0; kc < ICH/32; ++kc) {
        #pragma unroll
        for (int c = 0; c < 2; ++c) {
            int chunk = tid + c*256;
            int row = chunk >> 2;
            int c8  = (chunk & 3) * 8;
            *reinterpret_cast<uint4v*>(&Ash[row*XP_LDP + c8]) =
                *reinterpret_cast<const uint4v*>(&Ab[(size_t)(mb*128 + row)*ICH + kc*32 + c8]);
            int nrow = n0 + row;
            const unsigned short* bsrc = (nrow < N1)
                ? (W1b + (size_t)(layer*N1 + nrow)*KCAT + kc*32 + c8)
                : (W2b + (size_t)(layer*HCH + (nrow - N1))*KCAT + kc*32 + c8);
            *reinterpret_cast<uint4v*>(&Bsh[row*XP_LDP + c8]) =
                *reinterpret_cast<const uint4v*>(bsrc);
        }
        __syncthreads();
        bf16x8 af[4], bfr[4];
        #pragma unroll
        for (int mt=0; mt<4; ++mt)
            af[mt] = *reinterpret_cast<const bf16x8*>(&Ash[(wr + mt*16 + rfrag)*XP_LDP + koff]);
        #pragma unroll
        for (int nt=0; nt<4; ++nt)
            bfr[nt] = *reinterpret_cast<const bf16x8*>(&Bsh[(wc + nt*16 + rfrag)*XP_LDP + koff]);
        #pragma unroll
        for (int mt=0; mt<4; ++mt)
            #pragma unroll
            for (int nt=0; nt<4; ++nt)
                acc[mt][nt] = mfma_bf16(af[mt], bfr[nt], acc[mt][nt]);
        __syncthreads();
    }

    const int col0 = lane & 15;
    const int row0 = (lane >> 4) * 4;
    #pragma unroll
    for (int mt=0; mt<4; ++mt) {
        #pragma unroll
        for (int nt=0; nt<4; ++nt) {
            int n = n0 + wc + nt*16 + col0;
            #pragma unroll
            for (int r=0; r<4; ++r) {
                int m = mb*128 + wr + mt*16 + row0 + r;
                float v = acc[mt][nt][r];
                if (n < N1) {
                    v += b1[layer*N1 + n];
                    X1p[(size_t)m*N1 + n] = f2bf(v);
                } else {
                    v += b2[layer*HCH + (n - N1)];
                    X2p[(size_t)m*HCH + (n - N1)] = f2bf(v);
                }
            }
        }
    }
}

// ---------------------------------------------------------------- fast grid barrier
// ALL memory orders RELAXED: no buffer_wbl2 / buffer_inv on the critical path.
// Correctness: __syncthreads drains vmcnt(0) -> this WG's sc1 stores are at L3
// before the arrive fetch_add issues; gen only advances after all arrivals.
__device__ __forceinline__ void gbar(unsigned int* cnt, unsigned int* gen,
                                     unsigned int round) {
    __syncthreads();
    if (threadIdx.x == 0) {
        unsigned a = __hip_atomic_fetch_add(cnt, 1u, __ATOMIC_RELAXED,
                                            __HIP_MEMORY_SCOPE_AGENT);
        if (a == round*NWG - 1u) {
            __hip_atomic_store(gen, round, __ATOMIC_RELAXED,
                               __HIP_MEMORY_SCOPE_AGENT);
        } else {
            while (__hip_atomic_load(gen, __ATOMIC_RELAXED,
                                     __HIP_MEMORY_SCOPE_AGENT) < round)
                __builtin_amdgcn_s_sleep(1);
        }
    }
    __syncthreads();
}

// ---------------------------------------------------------------- fused recurrence
__global__ void __launch_bounds__(NTHR, 2)
rec_fused(const unsigned short* __restrict__ X1p,   // [32768][1024] bf16 (L0)
          const unsigned short* __restrict__ X2p,   // [32768][512]  bf16 (L0)
          const unsigned short* __restrict__ W1b,   // [L][1024][1024] bf16
          const unsigned short* __restrict__ W2b,   // [L][512][1024]  bf16
          const float* __restrict__ b1,
          const float* __restrict__ b2,
          const float* __restrict__ hiddens,        // [L][512]
          unsigned short* __restrict__ y0seq,       // [513][64][512] bf16
          unsigned short* __restrict__ h1b,         // [64][512] bf16
          unsigned short* __restrict__ rh0,         // [64][512] bf16
          unsigned short* __restrict__ rh1,         // [64][512] bf16
          float* __restrict__ out,                  // [512][64][512] f32
          float* __restrict__ hs,                   // [2][64][512]  f32
          unsigned int* __restrict__ cnt, unsigned int* __restrict__ gen) {
    __shared__ float zsh[BATCH*16];
    const int w     = blockIdx.x;
    const int tid   = threadIdx.x;
    const int lane  = tid & 63;
    const int v     = tid >> 6;
    const int rt    = v & 3;
    const int ct    = v >> 2;
    const int rfrag = lane & 15;
    const int quad  = lane >> 4;
    const int layer = (w >= 32) ? 1 : 0;
    const int c0    = (w & 31) * 16;
    const int arow  = rt*16 + rfrag;      // A-frag row (batch)
    const int crow  = rt*16 + quad*4;     // first owned C row
    const int ccol  = c0 + rfrag;         // owned col
    const int gcol  = (ct ? HCH : 0) + ccol;  // gate col in [0,1024)

    float hreg[4];
    #pragma unroll
    for (int r=0;r<4;++r) hreg[r] = hiddens[layer*HCH + ccol];
    const float bias1 = b1[(size_t)layer*N1 + gcol];   // used by L1 only
    const float bias2 = b2[(size_t)layer*HCH + ccol];  // used by L1 only

    // init h state (coherent pair-stores, even lanes carry (col, col+1))
    if (ct == 0) {
        unsigned short* dst = layer ? h1b : y0seq;     // y0seq slot 0
        #pragma unroll
        for (int r=0;r<4;++r) {
            unsigned short me = f2bf(hreg[r]);
            unsigned ot = (unsigned)__shfl_xor((int)(unsigned)me, 1, 64);
            if (!(lane & 1))
                st_word_co(&dst[(crow+r)*HCH + ccol], (unsigned)me | (ot << 16));
        }
    }
    unsigned rnd = 0;
    gbar(cnt, gen, ++rnd);

    for (int s = 0; s <= T_STEPS; ++s) {
        const int tt     = layer ? (s - 1) : s;           // this WG's timestep
        const int active = layer ? (s >= 1) : (s < T_STEPS);
        const unsigned short* aseq = y0seq + (size_t)s*BATCH*HCH;  // h0(t0-1) == y0(t1)

        // ---------------- phase A: gate pre-activations ----------------
        if (active) {
            floatx4 acc = (floatx4)(0.0f);
            const unsigned short* wrow = W1b + ((size_t)layer*N1 + gcol)*KCAT;
            if (!layer) {
                #pragma unroll
                for (int ks=0; ks<16; ++ks) {
                    bf16x8 a = ld_frag_co(&aseq[arow*HCH + ks*32 + quad*8]);
                    bf16x8 b = *reinterpret_cast<const bf16x8*>(&wrow[ICH + ks*32 + quad*8]);
                    acc = mfma_bf16(a, b, acc);
                }
            } else {
                #pragma unroll
                for (int ks=0; ks<16; ++ks) {           // k<512: y0(t1)
                    bf16x8 a = ld_frag_co(&aseq[arow*HCH + ks*32 + quad*8]);
                    bf16x8 b = *reinterpret_cast<const bf16x8*>(&wrow[ks*32 + quad*8]);
                    acc = mfma_bf16(a, b, acc);
                }
                #pragma unroll
                for (int ks=0; ks<16; ++ks) {           // k>=512: h1(t1-1)
                    bf16x8 a = ld_frag_co(&h1b[arow*HCH + ks*32 + quad*8]);
                    bf16x8 b = *reinterpret_cast<const bf16x8*>(&wrow[ICH + ks*32 + quad*8]);
                    acc = mfma_bf16(a, b, acc);
                }
            }
            float pre[4];
            if (!layer) {
                #pragma unroll
                for (int r=0;r<4;++r)
                    pre[r] = acc[r] + bf2f(X1p[(size_t)(tt*BATCH + crow + r)*N1 + gcol]);
            } else {
                #pragma unroll
                for (int r=0;r<4;++r) pre[r] = acc[r] + bias1;
            }
            if (ct == 0) {          // r-gate: rh = sigmoid(pre)*h  (h in regs)
                unsigned short* rbuf = layer ? rh1 : rh0;
                #pragma unroll
                for (int r=0;r<4;++r) {
                    float rh = sigmoidf_(pre[r]) * hreg[r];
                    unsigned short me = f2bf(rh);
                    unsigned ot = (unsigned)__shfl_xor((int)(unsigned)me, 1, 64);
                    if (!(lane & 1))
                        st_word_co(&rbuf[(crow+r)*HCH + ccol], (unsigned)me | (ot << 16));
                }
            } else {                // z-gate -> LDS
                #pragma unroll
                for (int r=0;r<4;++r)
                    zsh[(crow+r)*16 + rfrag] = sigmoidf_(pre[r]);
            }
        }
        gbar(cnt, gen, ++rnd);

        // ---------------- phase B: g = tanh(...), h update ----------------
        if (active && ct == 0) {
            floatx4 acc = (floatx4)(0.0f);
            const unsigned short* w2row = W2b + ((size_t)layer*HCH + ccol)*KCAT;
            const unsigned short* rbuf = layer ? rh1 : rh0;
            if (!layer) {
                #pragma unroll
                for (int ks=0; ks<16; ++ks) {
                    bf16x8 a = ld_frag_co(&rbuf[arow*HCH + ks*32 + quad*8]);
                    bf16x8 b = *reinterpret_cast<const bf16x8*>(&w2row[ICH + ks*32 + quad*8]);
                    acc = mfma_bf16(a, b, acc);
                }
            } else {
                #pragma unroll
                for (int ks=0; ks<16; ++ks) {           // k<512: y0(t1)
                    bf16x8 a = ld_frag_co(&aseq[arow*HCH + ks*32 + quad*8]);
                    bf16x8 b = *reinterpret_cast<const bf16x8*>(&w2row[ks*32 + quad*8]);
                    acc = mfma_bf16(a, b, acc);
                }
                #pragma unroll
                for (int ks=0; ks<16; ++ks) {           // k>=512: rh1
                    bf16x8 a = ld_frag_co(&rbuf[arow*HCH + ks*32 + quad*8]);
                    bf16x8 b = *reinterpret_cast<const bf16x8*>(&w2row[ICH + ks*32 + quad*8]);
                    acc = mfma_bf16(a, b, acc);
                }
            }
            unsigned short* hdst = layer ? h1b
                                         : (y0seq + (size_t)(tt+1)*BATCH*HCH);
            #pragma unroll
            for (int r=0;r<4;++r) {
                float x2 = layer ? bias2
                                 : bf2f(X2p[(size_t)(tt*BATCH + crow + r)*HCH + ccol]);
                float g  = tanhf(acc[r] + x2);
                float z  = zsh[(crow+r)*16 + rfrag];
                float hn = z*hreg[r] + (1.0f - z)*g;
                hreg[r] = hn;
                unsigned short me = f2bf(hn);
                unsigned ot = (unsigned)__shfl_xor((int)(unsigned)me, 1, 64);
                if (!(lane & 1))
                    st_word_co(&hdst[(crow+r)*HCH + ccol], (unsigned)me | (ot << 16));
                if (layer)
                    out[((size_t)tt*BATCH + crow + r)*HCH + ccol] = hn;
                if (tt == T_STEPS-1)
                    hs[(size_t)layer*BATCH*HCH + (crow+r)*HCH + ccol] = hn;
            }
        }
        gbar(cnt, gen, ++rnd);
    }
}

// ---------------------------------------------------------------- launch
extern "C" void kernel_launch(void* const* d_in, const int* in_sizes, int n_in,
                              void* d_out, int out_size, void* d_ws, size_t ws_size,
                              hipStream_t stream) {
    const float* x       = (const float*)d_in[0];
    const float* hiddens = (const float*)d_in[1];
    const float* W1      = (const float*)d_in[2];
    const float* b1      = (const float*)d_in[3];
    const float* W2      = (const float*)d_in[4];
    const float* b2      = (const float*)d_in[5];
    float* out = (float*)d_out;                    // [T][B][HC]
    float* hs  = out + (size_t)M_TOT*HCH;          // [L][B][HC]

    char* ws = (char*)d_ws;
    size_t off = 0;
    auto alloc = [&](size_t bytes) -> char* {
        char* p = ws + off; off += (bytes + 255) & ~(size_t)255; return p;
    };
    unsigned int*   bar   = (unsigned int*) alloc(1024);
    unsigned short* h1b   = (unsigned short*)alloc((size_t)BATCH*HCH*2);
    unsigned short* rh0   = (unsigned short*)alloc((size_t)BATCH*HCH*2);
    unsigned short* rh1   = (unsigned short*)alloc((size_t)BATCH*HCH*2);
    unsigned short* W1b   = (unsigned short*)alloc((size_t)NL*N1*KCAT*2);
    unsigned short* W2b   = (unsigned short*)alloc((size_t)NL*HCH*KCAT*2);
    unsigned short* xb    = (unsigned short*)alloc((size_t)M_TOT*ICH*2);
    unsigned short* X1p   = (unsigned short*)alloc((size_t)M_TOT*N1*2);
    unsigned short* X2p   = (unsigned short*)alloc((size_t)M_TOT*HCH*2);
    unsigned short* y0seq = (unsigned short*)alloc((size_t)(T_STEPS+1)*BATCH*HCH*2);

    hipMemsetAsync(bar, 0, 1024, stream);
    prep_kernel<<<2048, 256, 0, stream>>>(x, W1, W2, xb, W1b, W2b);
    xproj_kernel<<<dim3(12, 256), 256, 0, stream>>>(0, xb, W1b, W2b, b1, b2, X1p, X2p);
    // cnt at bar[0], gen at bar[64] (256B apart -> separate L3 lines)
    rec_fused<<<NWG, NTHR, 0, stream>>>(X1p, X2p, W1b, W2b, b1, b2, hiddens,
        y0seq, h1b, rh0, rh1, out, hs, bar, bar + 64);
}